// Round 8
// baseline (698.797 us; speedup 1.0000x reference)
//
#include <hip/hip_runtime.h>

#define BB 512
#define TT 1024
#define KK 48
#define NINF (-1e30f)

__device__ __forceinline__ float rfirst(float v) {
    return __int_as_float(__builtin_amdgcn_readfirstlane(__float_as_int(v)));
}

// One block per batch. Wave 0: forward (log-partition + gold score -> ws[b]).
// Wave 1: Viterbi, software-pipelined (argmax of step t runs inside step t+1),
// with lane-broadcasts issued on the LDS pipe (ds_bpermute, uniform index)
// so they overlap the previous step's VALU argmax work.
__global__ __launch_bounds__(128, 1) void crf_main(
    const float* __restrict__ em,    // [B][T][K]
    const int*   __restrict__ tags,  // [B][T]
    const float* __restrict__ st,    // [K]
    const float* __restrict__ en,    // [K]
    const float* __restrict__ tr,    // [K][K]
    float* __restrict__ out,         // [1 + B*T]
    float* __restrict__ ws)          // [B]
{
    __shared__ unsigned char s_bp[TT * KK];     // 49152 B (row 0 unused)
    __shared__ unsigned char s_path[TT];        // 1024 B

    const int b    = blockIdx.x;
    const int tid  = threadIdx.x;
    const int lane = tid & 63;
    const int wid  = tid >> 6;

    // opaque zero VGPR: ds_bpermute addr base; constant 4*i folds into offset:
    int zv;
    asm("v_mov_b32 %0, 0" : "=v"(zv));
#define BCF(src, i) __int_as_float(__builtin_amdgcn_ds_bpermute(                \
                        zv + 4 * (i), __float_as_int(src)))

    const float* emb = em + (size_t)b * TT * KK;
    const int*   tgb = tags + (size_t)b * TT;

    // sequence length (mask is a contiguous prefix)
    int cnt = 0;
    for (int t = lane; t < TT; t += 64) cnt += (tgb[t] > -1) ? 1 : 0;
#pragma unroll
    for (int off = 32; off >= 1; off >>= 1) cnt += __shfl_xor(cnt, off);
    const int len = cnt;  // >= 1

    const bool act = lane < KK;
    const int  jj  = act ? lane : (KK - 1);   // lanes 48-63 mirror lane 47

    const int S = len - 1;   // scan steps

    if (wid == 0) {
        // ---- gold path score: pure gather, t-parallel across lanes ----
        float sc = 0.f;
        for (int t = lane; t < len; t += 64) {
            int tg = tgb[t];
            sc += emb[t * KK + tg];
            if (t > 0) sc += tr[tgb[t - 1] * KK + tg];
        }
#pragma unroll
        for (int off = 32; off >= 1; off >>= 1) sc += __shfl_xor(sc, off);
        const float score = sc + st[tgb[0]] + en[tgb[len - 1]];

        // ---- forward scan, exp domain (validated R5-R7) ----
        float eTc[KK];  // exp(T[:, j])
#pragma unroll
        for (int i = 0; i < KK; ++i) eTc[i] = __expf(tr[i * KK + jj]);

        float a0 = st[jj] + emb[jj];
        float C  = rfirst(a0);
        float p  = __expf(a0 - C);

        float e[2];
        {
            int t1 = (1 < len) ? 1 : (len - 1);
            int t2 = (2 < len) ? 2 : (len - 1);
            e[1] = emb[(size_t)t1 * KK + jj];
            e[0] = emb[(size_t)t2 * KK + jj];
        }

#define FSTEP(t_, RENORM) {                                                  \
        const float eS = e[(t_) & 1];                                        \
        float z0 = 0.f, z1 = 0.f, z2 = 0.f, z3 = 0.f;                        \
        float z4 = 0.f, z5 = 0.f, z6 = 0.f, z7 = 0.f;                        \
        _Pragma("unroll")                                                    \
        for (int q = 0; q < 6; ++q) {                                        \
            z0 = fmaf(BCF(p, 8 * q + 0), eTc[8 * q + 0], z0);                \
            z1 = fmaf(BCF(p, 8 * q + 1), eTc[8 * q + 1], z1);                \
            z2 = fmaf(BCF(p, 8 * q + 2), eTc[8 * q + 2], z2);                \
            z3 = fmaf(BCF(p, 8 * q + 3), eTc[8 * q + 3], z3);                \
            z4 = fmaf(BCF(p, 8 * q + 4), eTc[8 * q + 4], z4);                \
            z5 = fmaf(BCF(p, 8 * q + 5), eTc[8 * q + 5], z5);                \
            z6 = fmaf(BCF(p, 8 * q + 6), eTc[8 * q + 6], z6);                \
            z7 = fmaf(BCF(p, 8 * q + 7), eTc[8 * q + 7], z7);                \
        }                                                                    \
        p = (((z0 + z1) + (z2 + z3)) + ((z4 + z5) + (z6 + z7)))              \
            * __expf(eS);                                                    \
        if (RENORM) {                                                        \
            float m = rfirst(p);                                             \
            p *= __frcp_rn(m);                                               \
            C += __logf(m);                                                  \
        }                                                                    \
        int tn = (t_) + 2; tn = (tn < len) ? tn : (len - 1);                 \
        e[(t_) & 1] = emb[(size_t)tn * KK + jj];                             \
    }

        {
            int t = 1;
            for (; t + 4 <= S + 1; t += 4) {
                FSTEP(t, 0) FSTEP(t + 1, 0) FSTEP(t + 2, 0) FSTEP(t + 3, 1)
            }
            for (; t <= S; ++t) FSTEP(t, 1)
        }
#undef FSTEP

        // logZ = C + log(sum_j p_j * exp(en_j))
        float y = act ? (p * __expf(en[jj])) : 0.f;
#pragma unroll
        for (int off = 32; off >= 1; off >>= 1) y += __shfl_xor(y, off);
        float logz = C + __logf(y);
        if (lane == 0) ws[b] = score - logz;
    } else {
        // ---------------- viterbi (bit-exact vs reference) ----------------
        float Tc[KK];  // T[:, j]
#pragma unroll
        for (int i = 0; i < KK; ++i) Tc[i] = tr[i * KK + jj];

        float av = st[jj] + emb[jj];

        float e[2];
        {
            int t1 = (1 < len) ? 1 : (len - 1);
            int t2 = (2 < len) ? 2 : (len - 1);
            e[1] = emb[(size_t)t1 * KK + jj];
            e[0] = emb[(size_t)t2 * KK + jj];
        }

        float xA[KK], xB[KK];
        float MA = 0.f, MB = 0.f;

// broadcast (LDS pipe) + add + exact max tree + recurrence (critical chain)
#define MAXPHASE(X, MV, t_) {                                                \
        const float eS = e[(t_) & 1];                                        \
        _Pragma("unroll")                                                    \
        for (int i = 0; i < KK; ++i) X[i] = BCF(av, i) + Tc[i];              \
        float l1[16];                                                        \
        _Pragma("unroll")                                                    \
        for (int q = 0; q < 16; ++q)                                         \
            l1[q] = fmaxf(fmaxf(X[3 * q], X[3 * q + 1]), X[3 * q + 2]);      \
        float l2[6];                                                         \
        _Pragma("unroll")                                                    \
        for (int q = 0; q < 5; ++q)                                          \
            l2[q] = fmaxf(fmaxf(l1[3 * q], l1[3 * q + 1]), l1[3 * q + 2]);   \
        l2[5] = l1[15];                                                      \
        MV = fmaxf(fmaxf(fmaxf(l2[0], l2[1]), l2[2]),                        \
                   fmaxf(fmaxf(l2[3], l2[4]), l2[5]));                       \
        av = MV + eS;                                                        \
        int tn = (t_) + 2; tn = (tn < len) ? tn : (len - 1);                 \
        e[(t_) & 1] = emb[(size_t)tn * KK + jj];                             \
    }

// first-occurrence argmax + backpointer store (off the critical chain;
// fills the NEXT step's broadcast/tree latency bubbles on the VALU pipe)
#define ARGPHASE(X, MV, t_) {                                                \
        int a0 = 255, a1 = 255, a2 = 255, a3 = 255;                          \
        _Pragma("unroll")                                                    \
        for (int i = 11; i >= 0; --i) {                                      \
            a0 = (X[i]      == MV) ? (i)      : a0;                          \
            a1 = (X[i + 12] == MV) ? (i + 12) : a1;                          \
            a2 = (X[i + 24] == MV) ? (i + 24) : a2;                          \
            a3 = (X[i + 36] == MV) ? (i + 36) : a3;                          \
        }                                                                    \
        int bi = min(min(a0, a1), min(a2, a3));                              \
        s_bp[(t_) * KK + jj] = (unsigned char)bi;  /* lanes>=48 dup ln47 */  \
    }

        if (S >= 1) {
            int t = 1;
            MAXPHASE(xA, MA, 1)
            while (t + 2 <= S) {
                MAXPHASE(xB, MB, t + 1)
                ARGPHASE(xA, MA, t)
                MAXPHASE(xA, MA, t + 2)
                ARGPHASE(xB, MB, t + 1)
                t += 2;
            }
            if (t + 1 <= S) {
                MAXPHASE(xB, MB, t + 1)
                ARGPHASE(xA, MA, t)
                ARGPHASE(xB, MB, t + 1)
            } else {
                ARGPHASE(xA, MA, t)
            }
        }
#undef MAXPHASE
#undef ARGPHASE

        // best last tag = argmax(alpha + end), first occurrence
        float v = act ? (av + en[jj]) : NINF;
        float M = v;
#pragma unroll
        for (int off = 32; off >= 1; off >>= 1) M = fmaxf(M, __shfl_xor(M, off));
        unsigned long long msk = __ballot(v == M);
        int cur = __ffsll(msk) - 1;
        s_path[len - 1] = (unsigned char)cur;   // cur uniform

        // register-row backtrack: lane l holds bp[t][l]; serial step is a
        // readlane instead of a dependent LDS load. 8-row batches.
        int t = len - 1;
        while (t >= 1) {
            const int n = (t < 8) ? t : 8;
            unsigned r[8];
#pragma unroll
            for (int k = 0; k < 8; ++k)
                r[k] = (k < n) ? (unsigned)s_bp[(t - k) * KK + jj] : 0u;
#pragma unroll
            for (int k = 0; k < 8; ++k) {
                if (k < n) {
                    cur = __builtin_amdgcn_readlane((int)r[k], cur);
                    if (lane == 0) s_path[t - k - 1] = (unsigned char)cur;
                }
            }
            t -= n;
        }

        // write tags (as floats; -1 where masked)
        float* ob = out + 1 + (size_t)b * TT;
        for (int tt = lane; tt < TT; tt += 64)
            ob[tt] = (tt < len) ? (float)s_path[tt] : -1.0f;
    }
#undef BCF
}

__global__ __launch_bounds__(512) void loss_reduce(const float* __restrict__ ws,
                                                   float* __restrict__ out)
{
    __shared__ float sh[8];
    const int lane = threadIdx.x & 63;
    const int w    = threadIdx.x >> 6;
    float s = ws[threadIdx.x];  // B == 512 == blockDim
#pragma unroll
    for (int off = 32; off >= 1; off >>= 1) s += __shfl_xor(s, off);
    if (lane == 0) sh[w] = s;
    __syncthreads();
    if (threadIdx.x == 0) {
        float tot = 0.f;
        for (int i = 0; i < 8; ++i) tot += sh[i];
        out[0] = -tot;
    }
}

extern "C" void kernel_launch(void* const* d_in, const int* in_sizes, int n_in,
                              void* d_out, int out_size, void* d_ws, size_t ws_size,
                              hipStream_t stream)
{
    const float* em   = (const float*)d_in[0];
    const int*   tags = (const int*)d_in[1];
    const float* st   = (const float*)d_in[2];
    const float* en   = (const float*)d_in[3];
    const float* tr   = (const float*)d_in[4];
    float* out = (float*)d_out;
    float* wsf = (float*)d_ws;

    hipLaunchKernelGGL(crf_main, dim3(BB), dim3(128), 0, stream,
                       em, tags, st, en, tr, out, wsf);
    hipLaunchKernelGGL(loss_reduce, dim3(1), dim3(512), 0, stream, wsf, out);
}

// Round 9
// 509.098 us; speedup vs baseline: 1.3726x; 1.3726x over previous
//
#include <hip/hip_runtime.h>

#define BB 512
#define TT 1024
#define KK 48
#define NINF (-1e30f)

__device__ __forceinline__ float rfirst(float v) {
    return __int_as_float(__builtin_amdgcn_readfirstlane(__float_as_int(v)));
}

// One block per batch. Wave 0: forward (log-partition + gold score -> ws[b]).
// Wave 1: Viterbi, software-pipelined (argmax of step t fills step t+1's
// dependency bubbles). Alpha broadcast: one ds_write_b32 + 12 uniform-address
// ds_read_b128 (LDS pipe, in-order per wave, conflict-free broadcast) instead
// of 48 VALU readlanes.
__global__ __launch_bounds__(128, 1) void crf_main(
    const float* __restrict__ em,    // [B][T][K]
    const int*   __restrict__ tags,  // [B][T]
    const float* __restrict__ st,    // [K]
    const float* __restrict__ en,    // [K]
    const float* __restrict__ tr,    // [K][K]
    float* __restrict__ out,         // [1 + B*T]
    float* __restrict__ ws)          // [B]
{
    __shared__ unsigned char s_bp[TT * KK];     // 49152 B (row 0 unused)
    __shared__ unsigned char s_path[TT];        // 1024 B
    __shared__ float s_avb[2][64];              // per-wave broadcast buffer

    const int b    = blockIdx.x;
    const int tid  = threadIdx.x;
    const int lane = tid & 63;
    const int wid  = tid >> 6;

    const float* emb = em + (size_t)b * TT * KK;
    const int*   tgb = tags + (size_t)b * TT;

    // sequence length (mask is a contiguous prefix)
    int cnt = 0;
    for (int t = lane; t < TT; t += 64) cnt += (tgb[t] > -1) ? 1 : 0;
#pragma unroll
    for (int off = 32; off >= 1; off >>= 1) cnt += __shfl_xor(cnt, off);
    const int len = cnt;  // >= 1

    const bool act = lane < KK;
    const int  jj  = act ? lane : (KK - 1);   // lanes 48-63 mirror lane 47

    const int S = len - 1;   // scan steps

    if (wid == 0) {
        // ---- gold path score: pure gather, t-parallel across lanes ----
        float sc = 0.f;
        for (int t = lane; t < len; t += 64) {
            int tg = tgb[t];
            sc += emb[t * KK + tg];
            if (t > 0) sc += tr[tgb[t - 1] * KK + tg];
        }
#pragma unroll
        for (int off = 32; off >= 1; off >>= 1) sc += __shfl_xor(sc, off);
        const float score = sc + st[tgb[0]] + en[tgb[len - 1]];

        // ---- forward scan, exp domain (validated R5-R8) ----
        float eTc[KK];  // exp(T[:, j])
#pragma unroll
        for (int i = 0; i < KK; ++i) eTc[i] = __expf(tr[i * KK + jj]);

        float a0 = st[jj] + emb[jj];
        float C  = rfirst(a0);
        float p  = __expf(a0 - C);

        const float4* S4 = (const float4*)(&s_avb[0][0]);

        float e[2];
        {
            int t1 = (1 < len) ? 1 : (len - 1);
            int t2 = (2 < len) ? 2 : (len - 1);
            e[1] = emb[(size_t)t1 * KK + jj];
            e[0] = emb[(size_t)t2 * KK + jj];
        }

#define FSTEP(t_, RENORM) {                                                  \
        const float eS = e[(t_) & 1];                                        \
        s_avb[0][lane] = p;            /* DS in-order: no barrier needed */  \
        float z0 = 0.f, z1 = 0.f, z2 = 0.f, z3 = 0.f;                        \
        float z4 = 0.f, z5 = 0.f, z6 = 0.f, z7 = 0.f;                        \
        _Pragma("unroll")                                                    \
        for (int q = 0; q < 6; ++q) {                                        \
            float4 v0 = S4[2 * q], v1 = S4[2 * q + 1];                       \
            z0 = fmaf(v0.x, eTc[8 * q + 0], z0);                             \
            z1 = fmaf(v0.y, eTc[8 * q + 1], z1);                             \
            z2 = fmaf(v0.z, eTc[8 * q + 2], z2);                             \
            z3 = fmaf(v0.w, eTc[8 * q + 3], z3);                             \
            z4 = fmaf(v1.x, eTc[8 * q + 4], z4);                             \
            z5 = fmaf(v1.y, eTc[8 * q + 5], z5);                             \
            z6 = fmaf(v1.z, eTc[8 * q + 6], z6);                             \
            z7 = fmaf(v1.w, eTc[8 * q + 7], z7);                             \
        }                                                                    \
        p = (((z0 + z1) + (z2 + z3)) + ((z4 + z5) + (z6 + z7)))              \
            * __expf(eS);                                                    \
        if (RENORM) {                                                        \
            float m = rfirst(p);                                             \
            p *= __frcp_rn(m);                                               \
            C += __logf(m);                                                  \
        }                                                                    \
        int tn = (t_) + 2; tn = (tn < len) ? tn : (len - 1);                 \
        e[(t_) & 1] = emb[(size_t)tn * KK + jj];                             \
    }

        {
            int t = 1;
            for (; t + 4 <= S + 1; t += 4) {
                FSTEP(t, 0) FSTEP(t + 1, 0) FSTEP(t + 2, 0) FSTEP(t + 3, 1)
            }
            for (; t <= S; ++t) FSTEP(t, 1)
        }
#undef FSTEP

        // logZ = C + log(sum_j p_j * exp(en_j))
        float y = act ? (p * __expf(en[jj])) : 0.f;
#pragma unroll
        for (int off = 32; off >= 1; off >>= 1) y += __shfl_xor(y, off);
        float logz = C + __logf(y);
        if (lane == 0) ws[b] = score - logz;
    } else {
        // ---------------- viterbi (bit-exact vs reference) ----------------
        float Tc[KK];  // T[:, j]
#pragma unroll
        for (int i = 0; i < KK; ++i) Tc[i] = tr[i * KK + jj];

        float av = st[jj] + emb[jj];

        const float4* S4 = (const float4*)(&s_avb[1][0]);

        float e[2];
        {
            int t1 = (1 < len) ? 1 : (len - 1);
            int t2 = (2 < len) ? 2 : (len - 1);
            e[1] = emb[(size_t)t1 * KK + jj];
            e[0] = emb[(size_t)t2 * KK + jj];
        }

        float xA[KK], xB[KK];
        float MA = 0.f, MB = 0.f;

// broadcast (LDS pipe: 1 write + 12 uniform b128 reads) + add + exact max
// tree + recurrence update (critical chain)
#define MAXPHASE(X, MV, t_) {                                                \
        const float eS = e[(t_) & 1];                                        \
        s_avb[1][lane] = av;           /* DS in-order: no barrier needed */  \
        _Pragma("unroll")                                                    \
        for (int q = 0; q < 12; ++q) {                                       \
            float4 v = S4[q];                                                \
            X[4 * q + 0] = v.x + Tc[4 * q + 0];                              \
            X[4 * q + 1] = v.y + Tc[4 * q + 1];                              \
            X[4 * q + 2] = v.z + Tc[4 * q + 2];                              \
            X[4 * q + 3] = v.w + Tc[4 * q + 3];                              \
        }                                                                    \
        float l1[16];                                                        \
        _Pragma("unroll")                                                    \
        for (int q = 0; q < 16; ++q)                                         \
            l1[q] = fmaxf(fmaxf(X[3 * q], X[3 * q + 1]), X[3 * q + 2]);      \
        float l2[6];                                                         \
        _Pragma("unroll")                                                    \
        for (int q = 0; q < 5; ++q)                                          \
            l2[q] = fmaxf(fmaxf(l1[3 * q], l1[3 * q + 1]), l1[3 * q + 2]);   \
        l2[5] = l1[15];                                                      \
        MV = fmaxf(fmaxf(fmaxf(l2[0], l2[1]), l2[2]),                        \
                   fmaxf(fmaxf(l2[3], l2[4]), l2[5]));                       \
        av = MV + eS;                                                        \
        int tn = (t_) + 2; tn = (tn < len) ? tn : (len - 1);                 \
        e[(t_) & 1] = emb[(size_t)tn * KK + jj];                             \
    }

// first-occurrence argmax + backpointer store, VGPR-pure (no v_cmp/VCC/SGPR):
// key_i = bits(x_i - M) | i. x==M -> +0.0 -> key=i; x<M -> sign bit set ->
// key >= 2^31. min over keys = smallest i achieving the max (exact).
#define ARGPHASE(X, MV, t_) {                                                \
        unsigned u[KK];                                                      \
        _Pragma("unroll")                                                    \
        for (int i = 0; i < KK; ++i)                                         \
            u[i] = (unsigned)__float_as_int(X[i] - MV) | (unsigned)i;        \
        unsigned m1[16];                                                     \
        _Pragma("unroll")                                                    \
        for (int q = 0; q < 16; ++q)                                         \
            m1[q] = min(min(u[3 * q], u[3 * q + 1]), u[3 * q + 2]);          \
        unsigned m2[6];                                                      \
        _Pragma("unroll")                                                    \
        for (int q = 0; q < 5; ++q)                                          \
            m2[q] = min(min(m1[3 * q], m1[3 * q + 1]), m1[3 * q + 2]);       \
        m2[5] = m1[15];                                                      \
        unsigned bi = min(min(min(m2[0], m2[1]), m2[2]),                     \
                          min(min(m2[3], m2[4]), m2[5]));                    \
        s_bp[(t_) * KK + jj] = (unsigned char)bi;  /* lanes>=48 dup ln47 */  \
    }

        if (S >= 1) {
            int t = 1;
            MAXPHASE(xA, MA, 1)
            while (t + 2 <= S) {
                MAXPHASE(xB, MB, t + 1)
                ARGPHASE(xA, MA, t)
                MAXPHASE(xA, MA, t + 2)
                ARGPHASE(xB, MB, t + 1)
                t += 2;
            }
            if (t + 1 <= S) {
                MAXPHASE(xB, MB, t + 1)
                ARGPHASE(xA, MA, t)
                ARGPHASE(xB, MB, t + 1)
            } else {
                ARGPHASE(xA, MA, t)
            }
        }
#undef MAXPHASE
#undef ARGPHASE

        // best last tag = argmax(alpha + end), first occurrence
        float v = act ? (av + en[jj]) : NINF;
        float M = v;
#pragma unroll
        for (int off = 32; off >= 1; off >>= 1) M = fmaxf(M, __shfl_xor(M, off));
        unsigned long long msk = __ballot(v == M);
        int cur = __ffsll(msk) - 1;
        s_path[len - 1] = (unsigned char)cur;   // cur uniform

        // register-row backtrack: lane l holds bp[t][l]; serial step is a
        // readlane instead of a dependent LDS load. 8-row batches.
        int t = len - 1;
        while (t >= 1) {
            const int n = (t < 8) ? t : 8;
            unsigned r[8];
#pragma unroll
            for (int k = 0; k < 8; ++k)
                r[k] = (k < n) ? (unsigned)s_bp[(t - k) * KK + jj] : 0u;
#pragma unroll
            for (int k = 0; k < 8; ++k) {
                if (k < n) {
                    cur = __builtin_amdgcn_readlane((int)r[k], cur);
                    if (lane == 0) s_path[t - k - 1] = (unsigned char)cur;
                }
            }
            t -= n;
        }

        // write tags (as floats; -1 where masked)
        float* ob = out + 1 + (size_t)b * TT;
        for (int tt = lane; tt < TT; tt += 64)
            ob[tt] = (tt < len) ? (float)s_path[tt] : -1.0f;
    }
}

__global__ __launch_bounds__(512) void loss_reduce(const float* __restrict__ ws,
                                                   float* __restrict__ out)
{
    __shared__ float sh[8];
    const int lane = threadIdx.x & 63;
    const int w    = threadIdx.x >> 6;
    float s = ws[threadIdx.x];  // B == 512 == blockDim
#pragma unroll
    for (int off = 32; off >= 1; off >>= 1) s += __shfl_xor(s, off);
    if (lane == 0) sh[w] = s;
    __syncthreads();
    if (threadIdx.x == 0) {
        float tot = 0.f;
        for (int i = 0; i < 8; ++i) tot += sh[i];
        out[0] = -tot;
    }
}

extern "C" void kernel_launch(void* const* d_in, const int* in_sizes, int n_in,
                              void* d_out, int out_size, void* d_ws, size_t ws_size,
                              hipStream_t stream)
{
    const float* em   = (const float*)d_in[0];
    const int*   tags = (const int*)d_in[1];
    const float* st   = (const float*)d_in[2];
    const float* en   = (const float*)d_in[3];
    const float* tr   = (const float*)d_in[4];
    float* out = (float*)d_out;
    float* wsf = (float*)d_ws;

    hipLaunchKernelGGL(crf_main, dim3(BB), dim3(128), 0, stream,
                       em, tags, st, en, tr, out, wsf);
    hipLaunchKernelGGL(loss_reduce, dim3(1), dim3(512), 0, stream, wsf, out);
}